// Round 10
// baseline (198.114 us; speedup 1.0000x reference)
//
#include <hip/hip_runtime.h>
#include <hip/hip_bf16.h>
#include <math.h>

#define B_ 2
#define S_ 1024
#define H_ 1024
#define NH_ 16
#define D_ 64
#define VOCAB 129

#define PSTR 72     // P LDS row stride (bf16)
#define QRSTR 136   // Qr/Pb LDS row stride (bf16)
#define OSTR 68     // partial-O combine stride (f32): 64 cols + pad

typedef __bf16 bf16_t;
typedef __bf16 bf16x8 __attribute__((ext_vector_type(8)));
typedef __bf16 bf16x4 __attribute__((ext_vector_type(4)));
typedef float f32x4 __attribute__((ext_vector_type(4)));

#define MFMA16(a, b, c) __builtin_amdgcn_mfma_f32_16x16x32_bf16(a, b, c, 0, 0, 0)
#define LGKM_FENCE() __asm__ volatile("s_waitcnt lgkmcnt(0)" ::: "memory")
#define GLL(gp, lp) __builtin_amdgcn_global_load_lds( \
    (const __attribute__((address_space(1))) void*)(gp), \
    (__attribute__((address_space(3))) void*)(lp), 16, 0, 0)

// ---------------------------------------------------------------------------
__global__ void build_tab_kernel(float* __restrict__ tab, bf16_t* __restrict__ tab_bf,
                                 bf16_t* __restrict__ tabT_bf) {
    int r = blockIdx.x;       // 0..143
    int d = threadIdx.x;      // 0..63
    float val = 0.f;
    if (r < VOCAB) {
        int p = d >> 1;
        float div = __expf((float)(2 * p) * (-logf(10000.0f) / (float)D_));
        float ang = (float)r * div;
        val = (d & 1) ? cosf(ang) : sinf(ang);
        tab[r * D_ + d] = val;
    }
    tab_bf[r * D_ + d] = (bf16_t)val;
    if (r < 128) tabT_bf[d * 128 + r] = (bf16_t)val;
}

// ---------------------------------------------------------------------------
__global__ __launch_bounds__(256) void cast_all_kernel(
        const float* __restrict__ hidden, const float* __restrict__ Wq,
        const float* __restrict__ Wk, const float* __restrict__ Wv,
        bf16_t* __restrict__ hidbf, bf16_t* __restrict__ wbf) {
    const int i = blockIdx.x * 256 + threadIdx.x;   // float4 index, < 1280K
    const int HID4 = 512 * 1024, W4 = 256 * 1024;
    const float* src;
    bf16_t* dst;
    int off;
    if (i < HID4)            { src = hidden; dst = hidbf;             off = i; }
    else if (i < HID4 + W4)  { src = Wq;     dst = wbf;               off = i - HID4; }
    else if (i < HID4 + 2*W4){ src = Wk;     dst = wbf + 1024*1024;   off = i - HID4 - W4; }
    else                     { src = Wv;     dst = wbf + 2*1024*1024; off = i - HID4 - 2*W4; }
    float4 v = ((const float4*)src)[off];
    bf16x4 o = {(bf16_t)v.x, (bf16_t)v.y, (bf16_t)v.z, (bf16_t)v.w};
    ((bf16x4*)dst)[off] = o;
}

// ---------------------------------------------------------------------------
// Fused QKV projection: 128(m) x 64(n) tile, BK=64, 768 blocks, 24 KB LDS.
// Q/K -> [B,NH,S,D] bf16;  V -> Vt [B,NH,D,S] bf16 (transposed via LDS).
// ---------------------------------------------------------------------------
__global__ __launch_bounds__(256) void proj_mfma_kernel(
        const bf16_t* __restrict__ Abf,   // [2048][1024]
        const bf16_t* __restrict__ Wbf,   // [3072][1024]  (Wq;Wk;Wv)
        const float* __restrict__ bq, const float* __restrict__ bk,
        const float* __restrict__ bv,
        bf16_t* __restrict__ Qbf, bf16_t* __restrict__ Kbf, bf16_t* __restrict__ Vt) {
    __shared__ __align__(16) char psmem[24576];
    bf16_t* As = (bf16_t*)psmem;              // 128 x 64 bf16 = 16 KB
    bf16_t* Bs = (bf16_t*)(psmem + 16384);    //  64 x 64 bf16 =  8 KB
    bf16_t* Es = (bf16_t*)psmem;              // epilogue staging (aliases As/Bs)

    const int tid = threadIdx.x;
    const int w = tid >> 6, l = tid & 63;
    const int n0 = blockIdx.x * 64, m0 = blockIdx.y * 128;
    const int wm = w & 1, wn = w >> 1;
    const int frow = l & 15;
    const int kq = (l >> 4) * 8;

    f32x4 acc[4][2] = {};

    for (int kt = 0; kt < H_; kt += 64) {
#pragma unroll
        for (int t = 0; t < 4; t++) {          // A: 1024 16B-chunks
            int c = t * 256 + tid;
            int row = c >> 3, ce = (c & 7) * 8;
            GLL(Abf + (size_t)(m0 + row) * H_ + kt + ce, (char*)As + c * 16);
        }
#pragma unroll
        for (int t = 0; t < 2; t++) {          // B: 512 16B-chunks
            int c = t * 256 + tid;
            int row = c >> 3, ce = (c & 7) * 8;
            GLL(Wbf + (size_t)(n0 + row) * H_ + kt + ce, (char*)Bs + c * 16);
        }
        __syncthreads();
#pragma unroll
        for (int h = 0; h < 2; h++) {
            bf16x8 af[4], bfr[2];
#pragma unroll
            for (int im = 0; im < 4; im++)
                af[im] = *(const bf16x8*)&As[(wm * 64 + im * 16 + frow) * 64 + h * 32 + kq];
#pragma unroll
            for (int in = 0; in < 2; in++)
                bfr[in] = *(const bf16x8*)&Bs[(wn * 32 + in * 16 + frow) * 64 + h * 32 + kq];
#pragma unroll
            for (int im = 0; im < 4; im++)
#pragma unroll
                for (int in = 0; in < 2; in++)
                    acc[im][in] = MFMA16(af[im], bfr[in], acc[im][in]);
        }
        __syncthreads();
    }

    const int proj = n0 >> 10;
    const int cn = l & 15, cr4 = (l >> 4) * 4;
    const int bb = m0 >> 10, mrem = m0 & 1023;
    const int nn = (n0 & 1023) >> 6;           // head index (tile is 64-aligned)

    if (proj < 2) {
        const float* bias = proj == 0 ? bq : bk;
        bf16_t* bdst = proj == 0 ? Qbf : Kbf;
#pragma unroll
        for (int im = 0; im < 4; im++) {
#pragma unroll
            for (int in = 0; in < 2; in++) {
                int nl = wn * 32 + in * 16 + cn;
                float bsv = bias[(n0 & 1023) + nl];
                int ml = wm * 64 + im * 16 + cr4;
#pragma unroll
                for (int vr = 0; vr < 4; vr++)
                    Es[(ml + vr) * 72 + nl] = (bf16_t)(acc[im][in][vr] + bsv);
            }
        }
        __syncthreads();
        bf16_t* base = bdst + (size_t)(bb * NH_ + nn) * S_ * D_ + (size_t)mrem * D_;
#pragma unroll
        for (int t = 0; t < 4; t++) {
            int c = t * 256 + tid;             // 128 rows x 8 chunks
            int ml = c >> 3, c8 = (c & 7) * 8;
            *(bf16x8*)&base[(size_t)ml * D_ + c8] = *(const bf16x8*)&Es[ml * 72 + c8];
        }
    } else {
        bf16_t* EsV = Es;                      // [64 d][136 m-pad]
#pragma unroll
        for (int im = 0; im < 4; im++) {
#pragma unroll
            for (int in = 0; in < 2; in++) {
                int nl = wn * 32 + in * 16 + cn;   // dd
                float bsv = bv[(n0 & 1023) + nl];
                int ml = wm * 64 + im * 16 + cr4;
                bf16x4 pv = {(bf16_t)(acc[im][in][0] + bsv), (bf16_t)(acc[im][in][1] + bsv),
                             (bf16_t)(acc[im][in][2] + bsv), (bf16_t)(acc[im][in][3] + bsv)};
                *(bf16x4*)&EsV[nl * 136 + ml] = pv;
            }
        }
        __syncthreads();
        bf16_t* base = Vt + (size_t)(bb * NH_ + nn) * D_ * S_ + mrem;
#pragma unroll
        for (int t = 0; t < 4; t++) {
            int c = t * 256 + tid;             // 64 rows(d) x 16 chunks
            int dd = c >> 4, s8 = (c & 15) * 8;
            *(bf16x8*)&base[(size_t)dd * S_ + s8] = *(const bf16x8*)&EsV[dd * 136 + s8];
        }
    }
}

// ---------------------------------------------------------------------------
// MFMA attention: block = 16 queries of one (b,h); wave w covers keys
// [w*256, w*256+256). 22.6 KB LDS (Osh aliased over P/Qr) -> 7 blocks/CU.
// Epilogue stores ALL 4 accumulator tiles to LDS with constant indices and
// reads combine inputs from LDS — NEVER index a register array with a
// runtime value (even via switch: SimplifyCFG sinks it back to a dynamic
// index -> whole accumulator demotes to scratch; r7-r9 regression).
// ---------------------------------------------------------------------------
__global__ __launch_bounds__(256, 4) void attn_mfma_kernel(
        const bf16_t* __restrict__ Qbf, const bf16_t* __restrict__ Kbf,
        const bf16_t* __restrict__ Vt,  const bf16_t* __restrict__ tab_bf,
        const bf16_t* __restrict__ tabT_bf, const float* __restrict__ tab,
        const float* __restrict__ mask, float* __restrict__ out) {
    // phase 1: [0,9216) P (4 waves x 16 x PSTR bf16); [9216,13568) Qr
    // phase 2: [0,17408) Osh (4 waves x 16 x OSTR f32) -- aliases P+Qr
    // always : [17408,21760) Pb; [21760,22528) SArr; [22528,22656) Ptail
    __shared__ __align__(16) char smem[22656];
    bf16_t* Pall  = (bf16_t*)smem;
    bf16_t* Qr    = (bf16_t*)(smem + 9216);
    float*  Osh   = (float*)smem;
    bf16_t* Pb    = (bf16_t*)(smem + 17408);
    float*  SArr  = (float*)(smem + 21760);   // [4][16][3]
    float*  Ptail = (float*)(smem + 22528);   // [16][2]

    const int tid = threadIdx.x;
    const int w = tid >> 6, l = tid & 63;
    const int lr = l & 15;
    const int lk = (l >> 4) * 8;
    const int reg4 = (l >> 4) * 4;

    const int gid = blockIdx.x;
    const int hl = gid & 31;            // same head -> same XCD (L2 locality)
    const int qblk = gid >> 5;
    const int b = hl >> 4, h = hl & 15;
    const int q0 = qblk * 16;

    const size_t bh = (size_t)(b * NH_ + h);
    const bf16_t* Qh = Qbf + bh * S_ * D_;
    const bf16_t* Kh = Kbf + bh * S_ * D_;
    const bf16_t* Vh = Vt + bh * D_ * S_;
    const float* mrow = mask + b * S_;
    bf16_t* myP = Pall + w * 16 * PSTR;

    // zero Pb + Ptail
    for (int e = tid; e < 16 * QRSTR / 2; e += 256) ((unsigned*)Pb)[e] = 0u;
    if (tid < 32) Ptail[tid] = 0.f;

    // Q A-frags (same addresses in all waves -> L1 hits)
    bf16x8 af0 = *(const bf16x8*)&Qh[(size_t)(q0 + lr) * D_ + lk];
    bf16x8 af1 = *(const bf16x8*)&Qh[(size_t)(q0 + lr) * D_ + 32 + lk];

    // Qr[i][r] = q_i . tab[r], n-tiles split across waves
    for (int nt = w; nt < 9; nt += 4) {
        f32x4 qa = {0.f, 0.f, 0.f, 0.f};
        const bf16_t* tb = tab_bf + (size_t)(nt * 16 + lr) * D_;
        qa = MFMA16(af0, *(const bf16x8*)&tb[lk], qa);
        qa = MFMA16(af1, *(const bf16x8*)&tb[32 + lk], qa);
        int col = nt * 16 + lr;
        if (col <= 128) {
#pragma unroll
            for (int r = 0; r < 4; r++) Qr[(reg4 + r) * QRSTR + col] = (bf16_t)qa[r];
        }
    }
    __syncthreads();

    float QrLo[4], QrHi[4];
#pragma unroll
    for (int r = 0; r < 4; r++) {
        QrLo[r] = (float)Qr[(reg4 + r) * QRSTR + 0];
        QrHi[r] = (float)Qr[(reg4 + r) * QRSTR + 128];
    }

    f32x4 oacc[5] = {};   // 4 d-tiles + stats (col0=lsum, col1=plo_pure, col2=phi_pure)
    const int kbase = w * 256;

    for (int kt = 0; kt < 4; kt++) {
        const int k0 = kbase + kt * 64;
        const bool allLo = (k0 + 63 - q0 <= -64);
        const bool allHi = (k0 - (q0 + 15) >= 64);
        const bool mixed = !(allLo || allHi);

        // mask
        float mj[4];
#pragma unroll
        for (int nt = 0; nt < 4; nt++) mj[nt] = mrow[k0 + nt * 16 + lr];

        // S = Q K^T (two k-halves, kf reused to cap liveness)
        f32x4 sac[4] = {};
        {
            bf16x8 kf[4];
#pragma unroll
            for (int nt = 0; nt < 4; nt++)
                kf[nt] = *(const bf16x8*)&Kh[(size_t)(k0 + nt * 16 + lr) * D_ + lk];
#pragma unroll
            for (int nt = 0; nt < 4; nt++) sac[nt] = MFMA16(af0, kf[nt], sac[nt]);
#pragma unroll
            for (int nt = 0; nt < 4; nt++)
                kf[nt] = *(const bf16x8*)&Kh[(size_t)(k0 + nt * 16 + lr) * D_ + 32 + lk];
#pragma unroll
            for (int nt = 0; nt < 4; nt++) sac[nt] = MFMA16(af1, kf[nt], sac[nt]);
        }

        // prefetch V (both k-halves) before the transform to cover latency
        bf16x8 vf[8];
#pragma unroll
        for (int nt = 0; nt < 4; nt++) {
            const bf16_t* vb = Vh + (size_t)(nt * 16 + lr) * S_ + k0;
            vf[2 * nt]     = *(const bf16x8*)&vb[lk];
            vf[2 * nt + 1] = *(const bf16x8*)&vb[32 + lk];
        }

        // transform: rel add, exp, bucket bookkeeping, P -> LDS
#pragma unroll
        for (int nt = 0; nt < 4; nt++) {
            int gj = k0 + nt * 16 + lr;
#pragma unroll
            for (int r = 0; r < 4; r++) {
                int gi = q0 + reg4 + r;
                float rel;
                if (allLo) rel = QrLo[r];
                else if (allHi) rel = QrHi[r];
                else {
                    int off = gj - gi;
                    off = off < -64 ? -64 : (off > 64 ? 64 : off);
                    rel = (float)Qr[(reg4 + r) * QRSTR + off + 64];
                }
                float p = __expf((sac[nt][r] + rel) * 0.125f + mj[nt]);
                if (mixed) {
                    int off = gj - gi;
                    if (off <= -64)      atomicAdd(&Ptail[(reg4 + r) * 2 + 0], p);
                    else if (off >= 64)  atomicAdd(&Ptail[(reg4 + r) * 2 + 1], p);
                    else                 Pb[(reg4 + r) * QRSTR + off + 64] = (bf16_t)p;
                }
                myP[(reg4 + r) * PSTR + nt * 16 + lr] = (bf16_t)p;
            }
        }
        LGKM_FENCE();

        float ov = (lr == 0) ? 1.f : (lr == 1) ? (allLo ? 1.f : 0.f)
                 : (lr == 2) ? (allHi ? 1.f : 0.f) : 0.f;
        bf16_t ob = (bf16_t)ov;
        bf16x8 onesf = {ob, ob, ob, ob, ob, ob, ob, ob};

        bf16x8 pa0 = *(const bf16x8*)&myP[lr * PSTR + lk];
        bf16x8 pa1 = *(const bf16x8*)&myP[lr * PSTR + 32 + lk];
#pragma unroll
        for (int nt = 0; nt < 4; nt++) {
            oacc[nt] = MFMA16(pa0, vf[2 * nt], oacc[nt]);
            oacc[nt] = MFMA16(pa1, vf[2 * nt + 1], oacc[nt]);
        }
        oacc[4] = MFMA16(pa0, onesf, oacc[4]);
        oacc[4] = MFMA16(pa1, onesf, oacc[4]);
    }

    __syncthreads();   // all P/Qr reads done everywhere; alias region now Osh

    // stats + ALL 4 partial-O tiles -> LDS (constant register indices only)
    if (lr < 3) {
#pragma unroll
        for (int r = 0; r < 4; r++) SArr[(w * 16 + reg4 + r) * 3 + lr] = oacc[4][r];
    }
#pragma unroll
    for (int nt = 0; nt < 4; nt++) {
#pragma unroll
        for (int r = 0; r < 4; r++)
            Osh[w * (16 * OSTR) + (reg4 + r) * OSTR + nt * 16 + lr] = oacc[nt][r];
    }
    __syncthreads();

    // wave w owns d-tile w: sum the 4 partials from LDS, add rel-value GEMM
    f32x4 c = {};
#pragma unroll
    for (int wo = 0; wo < 4; wo++) {
#pragma unroll
        for (int r = 0; r < 4; r++)
            c[r] += Osh[wo * (16 * OSTR) + (reg4 + r) * OSTR + w * 16 + lr];
    }
#pragma unroll
    for (int kc = 0; kc < 4; kc++) {
        bf16x8 pa = *(const bf16x8*)&Pb[lr * QRSTR + kc * 32 + lk];
        bf16x8 tb = *(const bf16x8*)&tabT_bf[(size_t)(w * 16 + lr) * 128 + kc * 32 + lk];
        c = MFMA16(pa, tb, c);
    }

#pragma unroll
    for (int r = 0; r < 4; r++) {
        int row = reg4 + r, gi = q0 + row;
        float ls  = SArr[row * 3]            + SArr[(16 + row) * 3]
                  + SArr[(32 + row) * 3]     + SArr[(48 + row) * 3];
        float plo = SArr[row * 3 + 1]        + SArr[(16 + row) * 3 + 1]
                  + SArr[(32 + row) * 3 + 1] + SArr[(48 + row) * 3 + 1]
                  + Ptail[row * 2];
        float phi = SArr[row * 3 + 2]        + SArr[(16 + row) * 3 + 2]
                  + SArr[(32 + row) * 3 + 2] + SArr[(48 + row) * 3 + 2]
                  + Ptail[row * 2 + 1];
        int d = w * 16 + lr;
        float o = c[r] + plo * tab[d] + phi * tab[128 * D_ + d];
        out[((size_t)(b * S_ + gi) * NH_ + h) * D_ + d] = o / ls;
    }
}

// ---------------------------------------------------------------------------
extern "C" void kernel_launch(void* const* d_in, const int* in_sizes, int n_in,
                              void* d_out, int out_size, void* d_ws, size_t ws_size,
                              hipStream_t stream) {
    const float* hidden = (const float*)d_in[0];
    const float* mask   = (const float*)d_in[1];
    const float* Wq     = (const float*)d_in[2];
    const float* bq     = (const float*)d_in[3];
    const float* Wk     = (const float*)d_in[4];
    const float* bk     = (const float*)d_in[5];
    const float* Wv     = (const float*)d_in[6];
    const float* bv     = (const float*)d_in[7];
    float* out = (float*)d_out;

    char* wsb = (char*)d_ws;
    bf16_t* Qbf    = (bf16_t*)(wsb);                                // 4 MB
    bf16_t* Kbf    = (bf16_t*)(wsb + (4u << 20));                   // 4 MB
    bf16_t* Vt     = (bf16_t*)(wsb + (8u << 20));                   // 4 MB
    float*  tab    = (float*) (wsb + (12u << 20));                  // 33 KB
    bf16_t* tab_bf = (bf16_t*)(wsb + (12u << 20) + (64u << 10));    // 18.4 KB
    bf16_t* tabT   = (bf16_t*)(wsb + (12u << 20) + (96u << 10));    // 16 KB
    bf16_t* hidbf  = (bf16_t*)(wsb + (12u << 20) + (128u << 10));   // 4 MB
    bf16_t* wbf    = (bf16_t*)(wsb + (16u << 20) + (128u << 10));   // 6 MB

    build_tab_kernel<<<dim3(144), dim3(64), 0, stream>>>(tab, tab_bf, tabT);
    cast_all_kernel<<<dim3(5120), dim3(256), 0, stream>>>(hidden, Wq, Wk, Wv, hidbf, wbf);

    proj_mfma_kernel<<<dim3(3072 / 64, 2048 / 128), dim3(256), 0, stream>>>(
        hidbf, wbf, bq, bk, bv, Qbf, Kbf, Vt);

    attn_mfma_kernel<<<dim3((S_ / 16) * NH_ * B_), dim3(256), 0, stream>>>(
        Qbf, Kbf, Vt, tab_bf, tabT, tab, mask, out);
}

// Round 11
// 177.814 us; speedup vs baseline: 1.1142x; 1.1142x over previous
//
#include <hip/hip_runtime.h>
#include <hip/hip_bf16.h>
#include <math.h>

#define B_ 2
#define S_ 1024
#define H_ 1024
#define NH_ 16
#define D_ 64
#define VOCAB 129

#define PSTR 72     // P LDS row stride (bf16)
#define QRSTR 136   // Qr/Pb LDS row stride (bf16)

typedef __bf16 bf16_t;
typedef __bf16 bf16x8 __attribute__((ext_vector_type(8)));
typedef __bf16 bf16x4 __attribute__((ext_vector_type(4)));
typedef float f32x4 __attribute__((ext_vector_type(4)));

#define MFMA16(a, b, c) __builtin_amdgcn_mfma_f32_16x16x32_bf16(a, b, c, 0, 0, 0)
#define LGKM_FENCE() __asm__ volatile("s_waitcnt lgkmcnt(0)" ::: "memory")
#define GLL(gp, lp) __builtin_amdgcn_global_load_lds( \
    (const __attribute__((address_space(1))) void*)(gp), \
    (__attribute__((address_space(3))) void*)(lp), 16, 0, 0)

// ---------------------------------------------------------------------------
// Fused: blocks [0,5120) cast hidden/Wq/Wk/Wv f32->bf16; blocks [5120,5156)
// build the sinusoid tables (tab f32 [129][64], tab_bf [144][64], tabT [64][128]).
// ---------------------------------------------------------------------------
__global__ __launch_bounds__(256) void cast_tab_kernel(
        const float* __restrict__ hidden, const float* __restrict__ Wq,
        const float* __restrict__ Wk, const float* __restrict__ Wv,
        bf16_t* __restrict__ hidbf, bf16_t* __restrict__ wbf,
        float* __restrict__ tab, bf16_t* __restrict__ tab_bf,
        bf16_t* __restrict__ tabT_bf) {
    const int bid = blockIdx.x;
    const int tid = threadIdx.x;
    if (bid >= 5120) {
        int r = (bid - 5120) * 4 + (tid >> 6);   // 0..143
        int d = tid & 63;
        float val = 0.f;
        if (r < VOCAB) {
            int p = d >> 1;
            float div = __expf((float)(2 * p) * (-logf(10000.0f) / (float)D_));
            float ang = (float)r * div;
            val = (d & 1) ? cosf(ang) : sinf(ang);
            tab[r * D_ + d] = val;
        }
        tab_bf[r * D_ + d] = (bf16_t)val;
        if (r < 128) tabT_bf[d * 128 + r] = (bf16_t)val;
        return;
    }
    const int i = bid * 256 + tid;   // float4 index, < 1280K
    const int HID4 = 512 * 1024, W4 = 256 * 1024;
    const float* src;
    bf16_t* dst;
    int off;
    if (i < HID4)            { src = hidden; dst = hidbf;             off = i; }
    else if (i < HID4 + W4)  { src = Wq;     dst = wbf;               off = i - HID4; }
    else if (i < HID4 + 2*W4){ src = Wk;     dst = wbf + 1024*1024;   off = i - HID4 - W4; }
    else                     { src = Wv;     dst = wbf + 2*1024*1024; off = i - HID4 - 2*W4; }
    float4 v = ((const float4*)src)[off];
    bf16x4 o = {(bf16_t)v.x, (bf16_t)v.y, (bf16_t)v.z, (bf16_t)v.w};
    ((bf16x4*)dst)[off] = o;
}

// ---------------------------------------------------------------------------
// Fused QKV projection: 128(m) x 64(n) tile, BK=64, 768 blocks, 24 KB LDS.
// Q/K -> [B,NH,S,D] bf16;  V -> Vt [B,NH,D,S] bf16 (transposed via LDS).
// ---------------------------------------------------------------------------
__global__ __launch_bounds__(256) void proj_mfma_kernel(
        const bf16_t* __restrict__ Abf,   // [2048][1024]
        const bf16_t* __restrict__ Wbf,   // [3072][1024]  (Wq;Wk;Wv)
        const float* __restrict__ bq, const float* __restrict__ bk,
        const float* __restrict__ bv,
        bf16_t* __restrict__ Qbf, bf16_t* __restrict__ Kbf, bf16_t* __restrict__ Vt) {
    __shared__ __align__(16) char psmem[24576];
    bf16_t* As = (bf16_t*)psmem;              // 128 x 64 bf16 = 16 KB
    bf16_t* Bs = (bf16_t*)(psmem + 16384);    //  64 x 64 bf16 =  8 KB
    bf16_t* Es = (bf16_t*)psmem;              // epilogue staging (aliases As/Bs)

    const int tid = threadIdx.x;
    const int w = tid >> 6, l = tid & 63;
    const int n0 = blockIdx.x * 64, m0 = blockIdx.y * 128;
    const int wm = w & 1, wn = w >> 1;
    const int frow = l & 15;
    const int kq = (l >> 4) * 8;

    f32x4 acc[4][2] = {};

    for (int kt = 0; kt < H_; kt += 64) {
#pragma unroll
        for (int t = 0; t < 4; t++) {          // A: 1024 16B-chunks
            int c = t * 256 + tid;
            int row = c >> 3, ce = (c & 7) * 8;
            GLL(Abf + (size_t)(m0 + row) * H_ + kt + ce, (char*)As + c * 16);
        }
#pragma unroll
        for (int t = 0; t < 2; t++) {          // B: 512 16B-chunks
            int c = t * 256 + tid;
            int row = c >> 3, ce = (c & 7) * 8;
            GLL(Wbf + (size_t)(n0 + row) * H_ + kt + ce, (char*)Bs + c * 16);
        }
        __syncthreads();
#pragma unroll
        for (int h = 0; h < 2; h++) {
            bf16x8 af[4], bfr[2];
#pragma unroll
            for (int im = 0; im < 4; im++)
                af[im] = *(const bf16x8*)&As[(wm * 64 + im * 16 + frow) * 64 + h * 32 + kq];
#pragma unroll
            for (int in = 0; in < 2; in++)
                bfr[in] = *(const bf16x8*)&Bs[(wn * 32 + in * 16 + frow) * 64 + h * 32 + kq];
#pragma unroll
            for (int im = 0; im < 4; im++)
#pragma unroll
                for (int in = 0; in < 2; in++)
                    acc[im][in] = MFMA16(af[im], bfr[in], acc[im][in]);
        }
        __syncthreads();
    }

    const int proj = n0 >> 10;
    const int cn = l & 15, cr4 = (l >> 4) * 4;
    const int bb = m0 >> 10, mrem = m0 & 1023;
    const int nn = (n0 & 1023) >> 6;           // head index (tile is 64-aligned)

    if (proj < 2) {
        const float* bias = proj == 0 ? bq : bk;
        bf16_t* bdst = proj == 0 ? Qbf : Kbf;
#pragma unroll
        for (int im = 0; im < 4; im++) {
#pragma unroll
            for (int in = 0; in < 2; in++) {
                int nl = wn * 32 + in * 16 + cn;
                float bsv = bias[(n0 & 1023) + nl];
                int ml = wm * 64 + im * 16 + cr4;
#pragma unroll
                for (int vr = 0; vr < 4; vr++)
                    Es[(ml + vr) * 72 + nl] = (bf16_t)(acc[im][in][vr] + bsv);
            }
        }
        __syncthreads();
        bf16_t* base = bdst + (size_t)(bb * NH_ + nn) * S_ * D_ + (size_t)mrem * D_;
#pragma unroll
        for (int t = 0; t < 4; t++) {
            int c = t * 256 + tid;             // 128 rows x 8 chunks
            int ml = c >> 3, c8 = (c & 7) * 8;
            *(bf16x8*)&base[(size_t)ml * D_ + c8] = *(const bf16x8*)&Es[ml * 72 + c8];
        }
    } else {
        bf16_t* EsV = Es;                      // [64 d][136 m-pad]
#pragma unroll
        for (int im = 0; im < 4; im++) {
#pragma unroll
            for (int in = 0; in < 2; in++) {
                int nl = wn * 32 + in * 16 + cn;   // dd
                float bsv = bv[(n0 & 1023) + nl];
                int ml = wm * 64 + im * 16 + cr4;
                bf16x4 pv = {(bf16_t)(acc[im][in][0] + bsv), (bf16_t)(acc[im][in][1] + bsv),
                             (bf16_t)(acc[im][in][2] + bsv), (bf16_t)(acc[im][in][3] + bsv)};
                *(bf16x4*)&EsV[nl * 136 + ml] = pv;
            }
        }
        __syncthreads();
        bf16_t* base = Vt + (size_t)(bb * NH_ + nn) * D_ * S_ + mrem;
#pragma unroll
        for (int t = 0; t < 4; t++) {
            int c = t * 256 + tid;             // 64 rows(d) x 16 chunks
            int dd = c >> 4, s8 = (c & 15) * 8;
            *(bf16x8*)&base[(size_t)dd * S_ + s8] = *(const bf16x8*)&EsV[dd * 136 + s8];
        }
    }
}

// ---------------------------------------------------------------------------
// MFMA attention — byte-for-byte the r6 configuration (measured 79 us,
// WRITE_SIZE == output exactly, i.e. zero spill): typed separate __shared__
// arrays (36.3 KB, 4 blocks/CU), block = 16 queries of one (b,h), wave w
// covers keys [w*256, w*256+256), grid 2048 with gid&31 head->XCD swizzle.
// DO NOT shrink the LDS footprint: smaller LDS flips the compiler's
// occupancy heuristic to 8 blocks/CU, caps VGPR at 64, and spills ~26
// dwords/thread (+55 MB HBM writes; r8-r10 regressions).
// ---------------------------------------------------------------------------
__global__ __launch_bounds__(256, 4) void attn_mfma_kernel(
        const bf16_t* __restrict__ Qbf, const bf16_t* __restrict__ Kbf,
        const bf16_t* __restrict__ Vt,  const bf16_t* __restrict__ tab_bf,
        const bf16_t* __restrict__ tabT_bf, const float* __restrict__ tab,
        const float* __restrict__ mask, float* __restrict__ out) {
    __shared__ __align__(16) bf16_t PlsA[4][16 * PSTR];   //  9.2 KB
    __shared__ __align__(16) bf16_t Qr[16 * QRSTR];       //  4.3 KB (block-shared)
    __shared__ __align__(16) bf16_t Pb[16 * QRSTR];       //  4.3 KB (block-shared)
    __shared__ float Ptail[16][2];                        //  0.13 KB
    __shared__ float SArr[4][16][3];                      //  0.8 KB
    __shared__ float Osh[4][16][68];                      // 17.4 KB

    const int tid = threadIdx.x;
    const int w = tid >> 6, l = tid & 63;
    const int lr = l & 15;
    const int lk = (l >> 4) * 8;
    const int reg4 = (l >> 4) * 4;

    const int gid = blockIdx.x;
    const int hl = gid & 31;            // same head -> same XCD (L2 locality)
    const int qblk = gid >> 5;
    const int b = hl >> 4, h = hl & 15;
    const int q0 = qblk * 16;

    const size_t bh = (size_t)(b * NH_ + h);
    const bf16_t* Qh = Qbf + bh * S_ * D_;
    const bf16_t* Kh = Kbf + bh * S_ * D_;
    const bf16_t* Vh = Vt + bh * D_ * S_;
    const float* mrow = mask + b * S_;
    bf16_t* myP = PlsA[w];

    // zero Pb + Ptail
    for (int e = tid; e < 16 * QRSTR / 2; e += 256) ((unsigned*)Pb)[e] = 0u;
    if (tid < 16) { Ptail[tid][0] = 0.f; Ptail[tid][1] = 0.f; }

    // Q A-frags (same addresses in all waves -> L1 hits)
    bf16x8 af0 = *(const bf16x8*)&Qh[(size_t)(q0 + lr) * D_ + lk];
    bf16x8 af1 = *(const bf16x8*)&Qh[(size_t)(q0 + lr) * D_ + 32 + lk];

    // Qr[i][r] = q_i . tab[r], n-tiles split across waves
    for (int nt = w; nt < 9; nt += 4) {
        f32x4 qa = {0.f, 0.f, 0.f, 0.f};
        const bf16_t* tb = tab_bf + (size_t)(nt * 16 + lr) * D_;
        qa = MFMA16(af0, *(const bf16x8*)&tb[lk], qa);
        qa = MFMA16(af1, *(const bf16x8*)&tb[32 + lk], qa);
        int col = nt * 16 + lr;
        if (col <= 128) {
#pragma unroll
            for (int r = 0; r < 4; r++) Qr[(reg4 + r) * QRSTR + col] = (bf16_t)qa[r];
        }
    }
    __syncthreads();

    float QrLo[4], QrHi[4];
#pragma unroll
    for (int r = 0; r < 4; r++) {
        QrLo[r] = (float)Qr[(reg4 + r) * QRSTR + 0];
        QrHi[r] = (float)Qr[(reg4 + r) * QRSTR + 128];
    }

    f32x4 oacc[5] = {};   // 4 d-tiles + stats (col0=lsum, col1=plo_pure, col2=phi_pure)
    const int kbase = w * 256;

    for (int kt = 0; kt < 4; kt++) {
        const int k0 = kbase + kt * 64;
        const bool allLo = (k0 + 63 - q0 <= -64);
        const bool allHi = (k0 - (q0 + 15) >= 64);
        const bool mixed = !(allLo || allHi);

        // mask
        float mj[4];
#pragma unroll
        for (int nt = 0; nt < 4; nt++) mj[nt] = mrow[k0 + nt * 16 + lr];

        // S = Q K^T (two k-halves, kf reused to cap liveness)
        f32x4 sac[4] = {};
        {
            bf16x8 kf[4];
#pragma unroll
            for (int nt = 0; nt < 4; nt++)
                kf[nt] = *(const bf16x8*)&Kh[(size_t)(k0 + nt * 16 + lr) * D_ + lk];
#pragma unroll
            for (int nt = 0; nt < 4; nt++) sac[nt] = MFMA16(af0, kf[nt], sac[nt]);
#pragma unroll
            for (int nt = 0; nt < 4; nt++)
                kf[nt] = *(const bf16x8*)&Kh[(size_t)(k0 + nt * 16 + lr) * D_ + 32 + lk];
#pragma unroll
            for (int nt = 0; nt < 4; nt++) sac[nt] = MFMA16(af1, kf[nt], sac[nt]);
        }

        // prefetch V (both k-halves) before the transform to cover latency
        bf16x8 vf[8];
#pragma unroll
        for (int nt = 0; nt < 4; nt++) {
            const bf16_t* vb = Vh + (size_t)(nt * 16 + lr) * S_ + k0;
            vf[2 * nt]     = *(const bf16x8*)&vb[lk];
            vf[2 * nt + 1] = *(const bf16x8*)&vb[32 + lk];
        }

        // transform: rel add, exp, bucket bookkeeping, P -> LDS
#pragma unroll
        for (int nt = 0; nt < 4; nt++) {
            int gj = k0 + nt * 16 + lr;
#pragma unroll
            for (int r = 0; r < 4; r++) {
                int gi = q0 + reg4 + r;
                float rel;
                if (allLo) rel = QrLo[r];
                else if (allHi) rel = QrHi[r];
                else {
                    int off = gj - gi;
                    off = off < -64 ? -64 : (off > 64 ? 64 : off);
                    rel = (float)Qr[(reg4 + r) * QRSTR + off + 64];
                }
                float p = __expf((sac[nt][r] + rel) * 0.125f + mj[nt]);
                if (mixed) {
                    int off = gj - gi;
                    if (off <= -64)      atomicAdd(&Ptail[reg4 + r][0], p);
                    else if (off >= 64)  atomicAdd(&Ptail[reg4 + r][1], p);
                    else                 Pb[(reg4 + r) * QRSTR + off + 64] = (bf16_t)p;
                }
                myP[(reg4 + r) * PSTR + nt * 16 + lr] = (bf16_t)p;
            }
        }
        LGKM_FENCE();

        float ov = (lr == 0) ? 1.f : (lr == 1) ? (allLo ? 1.f : 0.f)
                 : (lr == 2) ? (allHi ? 1.f : 0.f) : 0.f;
        bf16_t ob = (bf16_t)ov;
        bf16x8 onesf = {ob, ob, ob, ob, ob, ob, ob, ob};

        bf16x8 pa0 = *(const bf16x8*)&myP[lr * PSTR + lk];
        bf16x8 pa1 = *(const bf16x8*)&myP[lr * PSTR + 32 + lk];
#pragma unroll
        for (int nt = 0; nt < 4; nt++) {
            oacc[nt] = MFMA16(pa0, vf[2 * nt], oacc[nt]);
            oacc[nt] = MFMA16(pa1, vf[2 * nt + 1], oacc[nt]);
        }
        oacc[4] = MFMA16(pa0, onesf, oacc[4]);
        oacc[4] = MFMA16(pa1, onesf, oacc[4]);
    }

    // partials -> LDS (all 4 tiles, constant register indices)
    if (lr < 3) {
#pragma unroll
        for (int r = 0; r < 4; r++) SArr[w][reg4 + r][lr] = oacc[4][r];
    }
#pragma unroll
    for (int nt = 0; nt < 4; nt++)
#pragma unroll
        for (int r = 0; r < 4; r++) Osh[w][reg4 + r][nt * 16 + lr] = oacc[nt][r];
    __syncthreads();

    // wave w owns d-tile w: sum partials, add rel-value GEMM, tails, store
    f32x4 c = {};
#pragma unroll
    for (int r = 0; r < 4; r++)
        c[r] = Osh[0][reg4 + r][w * 16 + lr] + Osh[1][reg4 + r][w * 16 + lr] +
               Osh[2][reg4 + r][w * 16 + lr] + Osh[3][reg4 + r][w * 16 + lr];
#pragma unroll
    for (int kc = 0; kc < 4; kc++) {
        bf16x8 pa = *(const bf16x8*)&Pb[lr * QRSTR + kc * 32 + lk];
        bf16x8 tb = *(const bf16x8*)&tabT_bf[(size_t)(w * 16 + lr) * 128 + kc * 32 + lk];
        c = MFMA16(pa, tb, c);
    }

#pragma unroll
    for (int r = 0; r < 4; r++) {
        int row = reg4 + r, gi = q0 + row;
        float ls  = SArr[0][row][0] + SArr[1][row][0] + SArr[2][row][0] + SArr[3][row][0];
        float plo = SArr[0][row][1] + SArr[1][row][1] + SArr[2][row][1] + SArr[3][row][1]
                  + Ptail[row][0];
        float phi = SArr[0][row][2] + SArr[1][row][2] + SArr[2][row][2] + SArr[3][row][2]
                  + Ptail[row][1];
        int d = w * 16 + lr;
        float o = c[r] + plo * tab[d] + phi * tab[128 * D_ + d];
        out[((size_t)(b * S_ + gi) * NH_ + h) * D_ + d] = o / ls;
    }
}

// ---------------------------------------------------------------------------
extern "C" void kernel_launch(void* const* d_in, const int* in_sizes, int n_in,
                              void* d_out, int out_size, void* d_ws, size_t ws_size,
                              hipStream_t stream) {
    const float* hidden = (const float*)d_in[0];
    const float* mask   = (const float*)d_in[1];
    const float* Wq     = (const float*)d_in[2];
    const float* bq     = (const float*)d_in[3];
    const float* Wk     = (const float*)d_in[4];
    const float* bk     = (const float*)d_in[5];
    const float* Wv     = (const float*)d_in[6];
    const float* bv     = (const float*)d_in[7];
    float* out = (float*)d_out;

    char* wsb = (char*)d_ws;
    bf16_t* Qbf    = (bf16_t*)(wsb);                                // 4 MB
    bf16_t* Kbf    = (bf16_t*)(wsb + (4u << 20));                   // 4 MB
    bf16_t* Vt     = (bf16_t*)(wsb + (8u << 20));                   // 4 MB
    float*  tab    = (float*) (wsb + (12u << 20));                  // 33 KB
    bf16_t* tab_bf = (bf16_t*)(wsb + (12u << 20) + (64u << 10));    // 18.4 KB
    bf16_t* tabT   = (bf16_t*)(wsb + (12u << 20) + (96u << 10));    // 16 KB
    bf16_t* hidbf  = (bf16_t*)(wsb + (12u << 20) + (128u << 10));   // 4 MB
    bf16_t* wbf    = (bf16_t*)(wsb + (16u << 20) + (128u << 10));   // 6 MB

    cast_tab_kernel<<<dim3(5156), dim3(256), 0, stream>>>(
        hidden, Wq, Wk, Wv, hidbf, wbf, tab, tab_bf, tabT);

    proj_mfma_kernel<<<dim3(3072 / 64, 2048 / 128), dim3(256), 0, stream>>>(
        hidbf, wbf, bq, bk, bv, Qbf, Kbf, Vt);

    attn_mfma_kernel<<<dim3((S_ / 16) * NH_ * B_), dim3(256), 0, stream>>>(
        Qbf, Kbf, Vt, tab_bf, tabT, tab, mask, out);
}